// Round 5
// baseline (175.453 us; speedup 1.0000x reference)
//
#include <hip/hip_runtime.h>

// Fusion_loss: 3 modalities of Mahalanobis-distance softmax fusion.
// K=64 classes, Q=128 queries/class, DIM=1024. Rows M = 8192.
// logits_m[r][c] = -(||x_r||^2 - 2 x_r.p_c + ||p_c||^2) / var_c
// loss = mean_r sum_m w_m * (lse_m(r) - logits_m[r][y_r]),  y_r = r/128
// acc  = mean_r [argmax_c sum_m w_m softmax(logits_m)[r][c] == y_r]
//
// R5: the compiler keeps only ~1 VGPR load in flight per wave (VGPR=48
// across R2-R4; Little's law: 13 x 64B x 600cyc == the measured 880 GB/s).
// Fix: stage A via global_load_lds DMA (compiler cannot sink it; m97
// pattern: issue 8 x 1KB units -> __syncthreads drains vmcnt -> consume).
// Block = 2 waves sharing one (m, 16-row tile); unit stride 1056 B keeps
// ds_read A-frags at 4-way bank aliasing. Modalities decoupled: per-m
// pred -> 6MB ws, two-stage finalize (no same-address atomics).

typedef _Float16 half8 __attribute__((ext_vector_type(8)));
typedef float    floatx4 __attribute__((ext_vector_type(4)));

#define NCLS   64
#define QPC    128
#define DIM    1024
#define NROWS  (NCLS * QPC)      // 8192
#define NRT    (NROWS / 16)      // 512 row tiles
#define CHUNK  256               // k-cols staged per chunk
#define NCHUNK (DIM / CHUNK)     // 4
#define NKC    (CHUNK / 32)      // 8 MFMA k-steps per chunk
#define UW     264               // unit stride in words (1056 B): 264%32=8 -> 4-way banks

// ws layout
#define OFF_W    0                          // f16 protos, B-frag units
#define W_BYTES  (3 * NCLS * DIM * 2)       // 393216
#define OFF_P2   W_BYTES                    // 768 B
#define OFF_PRED 397312                     // padded to 4K
#define PRED_BYTES (3 * NROWS * NCLS * 4)   // 6291456
#define OFF_LOSS (OFF_PRED + PRED_BYTES)    // 1536 floats
#define OFF_CNT  (OFF_LOSS + 1536 * 4)      // 64 floats
#define WS_NEED  (OFF_CNT + 64 * 4)

__device__ __forceinline__ void dma16(const float* g, float* l) {
    __builtin_amdgcn_global_load_lds(
        (const __attribute__((address_space(1))) void*)g,
        (__attribute__((address_space(3))) void*)l,
        16, 0, 0);
}

// ---------------- prep: protos -> f16 B-frag layout + p2 ----------------
// Unit (m,kcg,t4) = 1KB: lane l=(l15,quad) holds 8 halves = col t4*16+l15,
// k = kcg*32 + quad*8 .. +8.
__global__ __launch_bounds__(64) void prep_protos(
    const float* __restrict__ Ptf, const float* __restrict__ Pde,
    const float* __restrict__ Pff, _Float16* __restrict__ W,
    float* __restrict__ p2)
{
    const int m    = blockIdx.x >> 5;
    const int kcg  = blockIdx.x & 31;
    const int lane = threadIdx.x;
    const int l15  = lane & 15;
    const int quad = lane >> 4;
    const float* __restrict__ P = (m == 0) ? Ptf : (m == 1) ? Pde : Pff;

    #pragma unroll
    for (int t = 0; t < 4; ++t) {
        const float* src = P + (size_t)(t * 16 + l15) * DIM + kcg * 32 + quad * 8;
        const float4 b0 = *reinterpret_cast<const float4*>(src);
        const float4 b1 = *reinterpret_cast<const float4*>(src + 4);
        half8 h;
        h[0] = (_Float16)b0.x; h[1] = (_Float16)b0.y;
        h[2] = (_Float16)b0.z; h[3] = (_Float16)b0.w;
        h[4] = (_Float16)b1.x; h[5] = (_Float16)b1.y;
        h[6] = (_Float16)b1.z; h[7] = (_Float16)b1.w;
        *reinterpret_cast<half8*>(W + ((size_t)(m * 32 + kcg) * 4 + t) * 512 + lane * 8) = h;

        float s = b0.x*b0.x + b0.y*b0.y + b0.z*b0.z + b0.w*b0.w
                + b1.x*b1.x + b1.y*b1.y + b1.z*b1.z + b1.w*b1.w;
        s += __shfl_xor(s, 16);
        s += __shfl_xor(s, 32);
        if (quad == 0) atomicAdd(&p2[m * 64 + t * 16 + l15], s);
    }
}

// ---------------- main: DMA-staged A, per-m pred/loss ----------------
__global__ __launch_bounds__(128) void fusion_main(
    const float* __restrict__ Xtf, const float* __restrict__ Vtf,
    const float* __restrict__ Xde, const float* __restrict__ Vde,
    const float* __restrict__ Xff, const float* __restrict__ Vff,
    const _Float16* __restrict__ W, const float* __restrict__ p2g,
    float* __restrict__ predOut,   // [3][8192][64]
    float* __restrict__ lossPart)  // [1536]
{
    __shared__ float chunkBuf[16 * UW];        // 16896 B, DMA-only writes
    __shared__ float mxW[2][16], sW[2][16];
    __shared__ float lossW[2];

    const int tid  = threadIdx.x;
    const int w    = tid >> 6;        // wave 0/1: cols w*32 .. w*32+31
    const int lane = tid & 63;
    const int l15  = lane & 15;
    const int quad = lane >> 4;
    const int m    = blockIdx.x >> 9;     // /512
    const int rt   = blockIdx.x & 511;
    const int rowBase = rt * 16;

    const float* __restrict__ X = (m == 0) ? Xtf : (m == 1) ? Xde : Xff;
    const float* __restrict__ V = (m == 0) ? Vtf : (m == 1) ? Vde : Vff;
    const float  wgt = (m == 0) ? 1.0f : (m == 1) ? 0.8f : 0.6f;

    floatx4 d[2];
    d[0] = (floatx4){0.f, 0.f, 0.f, 0.f};
    d[1] = (floatx4){0.f, 0.f, 0.f, 0.f};
    float x2p = 0.0f;   // partial ||x_row l15||^2 (this quad's k-slices)

    #pragma unroll 1
    for (int c = 0; c < NCHUNK; ++c) {
        __syncthreads();   // prev chunk fully consumed before overwrite
        // DMA 8 rows/wave: unit r = 1 KB lane-contiguous row slice
        const float* gbase = X + (size_t)rowBase * DIM + c * CHUNK + lane * 4;
        #pragma unroll
        for (int r8 = 0; r8 < 8; ++r8) {
            const int r = w * 8 + r8;
            dma16(gbase + (size_t)r * DIM, &chunkBuf[r * UW]);
        }
        __syncthreads();   // drains vmcnt(0): DMA complete + visible

        #pragma unroll
        for (int kc = 0; kc < NKC; ++kc) {
            const int off = l15 * UW + kc * 32 + quad * 8;
            const float4 a0 = *reinterpret_cast<const float4*>(&chunkBuf[off]);
            const float4 a1 = *reinterpret_cast<const float4*>(&chunkBuf[off + 4]);

            const int kcg = c * NKC + kc;
            half8 bf[2];
            #pragma unroll
            for (int t = 0; t < 2; ++t)
                bf[t] = *reinterpret_cast<const half8*>(
                    W + ((size_t)(m * 32 + kcg) * 4 + (w * 2 + t)) * 512 + lane * 8);

            x2p += a0.x*a0.x + a0.y*a0.y + a0.z*a0.z + a0.w*a0.w
                 + a1.x*a1.x + a1.y*a1.y + a1.z*a1.z + a1.w*a1.w;

            half8 af;
            af[0] = (_Float16)a0.x; af[1] = (_Float16)a0.y;
            af[2] = (_Float16)a0.z; af[3] = (_Float16)a0.w;
            af[4] = (_Float16)a1.x; af[5] = (_Float16)a1.y;
            af[6] = (_Float16)a1.z; af[7] = (_Float16)a1.w;

            d[0] = __builtin_amdgcn_mfma_f32_16x16x32_f16(af, bf[0], d[0], 0, 0, 0);
            d[1] = __builtin_amdgcn_mfma_f32_16x16x32_f16(af, bf[1], d[1], 0, 0, 0);
        }
    }

    // complete x2 across quads: every lane gets x2 of row l15
    x2p += __shfl_xor(x2p, 16);
    x2p += __shfl_xor(x2p, 32);
    float x2r[4];
    #pragma unroll
    for (int r = 0; r < 4; ++r) x2r[r] = __shfl(x2p, quad * 4 + r);

    float vc[2], p2c[2];
    #pragma unroll
    for (int t = 0; t < 2; ++t) {
        const int col = w * 32 + t * 16 + l15;
        vc[t]  = V[col];
        p2c[t] = p2g[m * 64 + col];
    }

    // logits for this wave's 32 cols x 16 rows (C-layout row = quad*4+r)
    float lg[4][2];
    #pragma unroll
    for (int r = 0; r < 4; ++r)
        #pragma unroll
        for (int t = 0; t < 2; ++t)
            lg[r][t] = (2.0f * d[t][r] - x2r[r] - p2c[t]) / vc[t];

    // cross-wave softmax: per-wave 32-col max -> LDS -> global max
    #pragma unroll
    for (int r = 0; r < 4; ++r) {
        float mx = fmaxf(lg[r][0], lg[r][1]);
        #pragma unroll
        for (int dl = 1; dl <= 8; dl <<= 1) mx = fmaxf(mx, __shfl_xor(mx, dl));
        if (l15 == 0) mxW[w][quad * 4 + r] = mx;
    }
    __syncthreads();
    float gmx[4];
    #pragma unroll
    for (int r = 0; r < 4; ++r) {
        const int row = quad * 4 + r;
        gmx[r] = fmaxf(mxW[0][row], mxW[1][row]);
        float s = expf(lg[r][0] - gmx[r]) + expf(lg[r][1] - gmx[r]);
        #pragma unroll
        for (int dl = 1; dl <= 8; dl <<= 1) s += __shfl_xor(s, dl);
        if (l15 == 0) sW[w][row] = s;
    }
    __syncthreads();

    const int y = rowBase >> 7;   // target class, uniform across block
    float lossAcc = 0.0f;
    #pragma unroll
    for (int r = 0; r < 4; ++r) {
        const int row = quad * 4 + r;
        const float lse = gmx[r] + logf(sW[0][row] + sW[1][row]);
        if (w == (y >> 5) && l15 == (y & 15))
            lossAcc += wgt * (lse - lg[r][(y >> 4) & 1]);
        const int R = rowBase + row;
        #pragma unroll
        for (int t = 0; t < 2; ++t)
            predOut[((size_t)m * NROWS + R) * 64 + w * 32 + t * 16 + l15] =
                wgt * expf(lg[r][t] - lse);
    }

    #pragma unroll
    for (int dl = 1; dl <= 32; dl <<= 1) lossAcc += __shfl_xor(lossAcc, dl);
    if (lane == 0) lossW[w] = lossAcc;
    __syncthreads();
    if (tid == 0) lossPart[blockIdx.x] = lossW[0] + lossW[1];
}

// ---------------- finalize1: fused argmax over 3-m pred ----------------
__global__ __launch_bounds__(256) void finalize1(
    const float* __restrict__ pred, float* __restrict__ cntPart)
{
    const int tid  = threadIdx.x;
    const int w    = tid >> 6;
    const int lane = tid & 63;
    float cnt = 0.0f;
    #pragma unroll 1
    for (int i = 0; i < 32; ++i) {
        const int R = blockIdx.x * 128 + w * 32 + i;
        float p = pred[(size_t)R * 64 + lane]
                + pred[((size_t)NROWS + R) * 64 + lane]
                + pred[((size_t)2 * NROWS + R) * 64 + lane];
        float bv = p; int bc = lane;
        #pragma unroll
        for (int dl = 1; dl <= 32; dl <<= 1) {
            const float ov = __shfl_xor(bv, dl);
            const int   oc = __shfl_xor(bc, dl);
            if (ov > bv || (ov == bv && oc < bc)) { bv = ov; bc = oc; }
        }
        if (lane == 0 && bc == (R >> 7)) cnt += 1.0f;
    }
    #pragma unroll
    for (int dl = 1; dl <= 32; dl <<= 1) cnt += __shfl_xor(cnt, dl);
    __shared__ float sc[4];
    if (lane == 0) sc[w] = cnt;
    __syncthreads();
    if (tid == 0) cntPart[blockIdx.x] = sc[0] + sc[1] + sc[2] + sc[3];
}

// ---------------- finalize2: scalar reduce ----------------
__global__ __launch_bounds__(256) void finalize2(
    const float* __restrict__ lossPart, const float* __restrict__ cntPart,
    float* __restrict__ out)
{
    const int tid  = threadIdx.x;
    const int lane = tid & 63;
    const int w    = tid >> 6;
    float l = 0.0f, c = 0.0f;
    for (int i = tid; i < 1536; i += 256) l += lossPart[i];
    if (tid < 64) c = cntPart[tid];
    #pragma unroll
    for (int dl = 1; dl <= 32; dl <<= 1) {
        l += __shfl_xor(l, dl);
        c += __shfl_xor(c, dl);
    }
    __shared__ float sl[4], sc[4];
    if (lane == 0) { sl[w] = l; sc[w] = c; }
    __syncthreads();
    if (tid == 0) {
        out[0] = (sl[0] + sl[1] + sl[2] + sl[3]) * (1.0f / NROWS);
        out[1] = (sc[0] + sc[1] + sc[2] + sc[3]) * (1.0f / NROWS);
    }
}

// ---------------- fallback (R2 kernel, self-contained) ----------------
#define NWAVES 12
#define KSPLIT 4
#define KSLICE (DIM / KSPLIT)
#define NITER  (KSLICE / 32)
#define DSTRIDE 17
#define PSTRIDE 65

__global__ __launch_bounds__(NWAVES * 64) void fusion_loss_fallback(
    const float* __restrict__ Xtf, const float* __restrict__ Ptf, const float* __restrict__ Vtf,
    const float* __restrict__ Xde, const float* __restrict__ Pde, const float* __restrict__ Vde,
    const float* __restrict__ Xff, const float* __restrict__ Pff, const float* __restrict__ Vff,
    float* __restrict__ out)
{
    __shared__ float dpart[NWAVES][64 * DSTRIDE];
    __shared__ float x2part[NWAVES][16];
    __shared__ float p2part[NWAVES][64];
    __shared__ float predL[16 * PSTRIDE];
    __shared__ float lossL;

    const int tid  = threadIdx.x;
    const int wave = tid >> 6;
    const int lane = tid & 63;
    const int l15  = lane & 15;
    const int quad = lane >> 4;
    const int m    = wave >> 2;
    const int kq   = wave & 3;
    const int rowBase = blockIdx.x * 16;

    for (int i = tid; i < 16 * PSTRIDE; i += NWAVES * 64) predL[i] = 0.0f;
    if (tid == 0) lossL = 0.0f;

    const float* __restrict__ X = (m == 0) ? Xtf : (m == 1) ? Xde : Xff;
    const float* __restrict__ P = (m == 0) ? Ptf : (m == 1) ? Pde : Pff;
    const float* __restrict__ V = (m == 0) ? Vtf : (m == 1) ? Vde : Vff;
    const float  w = (m == 0) ? 1.0f : (m == 1) ? 0.8f : 0.6f;

    floatx4 d[4];
    #pragma unroll
    for (int t = 0; t < 4; ++t) d[t] = (floatx4){0.f, 0.f, 0.f, 0.f};
    float x2p    = 0.0f;
    float p2p[4] = {0.f, 0.f, 0.f, 0.f};

    const float* xrow = X + (size_t)(rowBase + l15) * DIM + kq * KSLICE + quad * 8;
    const float* prow[4];
    #pragma unroll
    for (int t = 0; t < 4; ++t)
        prow[t] = P + (size_t)(t * 16 + l15) * DIM + kq * KSLICE + quad * 8;

    #pragma unroll 2
    for (int kc = 0; kc < NITER; ++kc) {
        const int ko = kc * 32;
        const float4 a0 = *reinterpret_cast<const float4*>(xrow + ko);
        const float4 a1 = *reinterpret_cast<const float4*>(xrow + ko + 4);
        float4 b0[4], b1[4];
        #pragma unroll
        for (int t = 0; t < 4; ++t) {
            b0[t] = *reinterpret_cast<const float4*>(prow[t] + ko);
            b1[t] = *reinterpret_cast<const float4*>(prow[t] + ko + 4);
        }
        x2p += a0.x*a0.x + a0.y*a0.y + a0.z*a0.z + a0.w*a0.w
             + a1.x*a1.x + a1.y*a1.y + a1.z*a1.z + a1.w*a1.w;
        half8 af;
        af[0] = (_Float16)a0.x; af[1] = (_Float16)a0.y;
        af[2] = (_Float16)a0.z; af[3] = (_Float16)a0.w;
        af[4] = (_Float16)a1.x; af[5] = (_Float16)a1.y;
        af[6] = (_Float16)a1.z; af[7] = (_Float16)a1.w;
        #pragma unroll
        for (int t = 0; t < 4; ++t) {
            p2p[t] += b0[t].x*b0[t].x + b0[t].y*b0[t].y + b0[t].z*b0[t].z + b0[t].w*b0[t].w
                    + b1[t].x*b1[t].x + b1[t].y*b1[t].y + b1[t].z*b1[t].z + b1[t].w*b1[t].w;
            half8 bf;
            bf[0] = (_Float16)b0[t].x; bf[1] = (_Float16)b0[t].y;
            bf[2] = (_Float16)b0[t].z; bf[3] = (_Float16)b0[t].w;
            bf[4] = (_Float16)b1[t].x; bf[5] = (_Float16)b1[t].y;
            bf[6] = (_Float16)b1[t].z; bf[7] = (_Float16)b1[t].w;
            d[t] = __builtin_amdgcn_mfma_f32_16x16x32_f16(af, bf, d[t], 0, 0, 0);
        }
    }

    x2p += __shfl_xor(x2p, 16);
    x2p += __shfl_xor(x2p, 32);
    #pragma unroll
    for (int t = 0; t < 4; ++t) {
        p2p[t] += __shfl_xor(p2p[t], 16);
        p2p[t] += __shfl_xor(p2p[t], 32);
    }
    {
        float* dp = &dpart[wave][lane * DSTRIDE];
        #pragma unroll
        for (int t = 0; t < 4; ++t)
            *reinterpret_cast<float4*>(dp + t * 4) =
                make_float4(d[t][0], d[t][1], d[t][2], d[t][3]);
        if (quad == 0) {
            x2part[wave][l15] = x2p;
            #pragma unroll
            for (int t = 0; t < 4; ++t) p2part[wave][t * 16 + l15] = p2p[t];
        }
    }
    __syncthreads();

    const int y = rowBase >> 7;

    if (kq == 0) {
        floatx4 dsum[4];
        #pragma unroll
        for (int t = 0; t < 4; ++t) dsum[t] = (floatx4){0.f, 0.f, 0.f, 0.f};
        float x2r[4] = {0.f, 0.f, 0.f, 0.f};
        float p2c[4] = {0.f, 0.f, 0.f, 0.f};
        #pragma unroll
        for (int k2 = 0; k2 < KSPLIT; ++k2) {
            const int wv = m * 4 + k2;
            const float* src = &dpart[wv][lane * DSTRIDE];
            #pragma unroll
            for (int t = 0; t < 4; ++t) {
                const float4 v = *reinterpret_cast<const float4*>(src + t * 4);
                dsum[t][0] += v.x; dsum[t][1] += v.y; dsum[t][2] += v.z; dsum[t][3] += v.w;
            }
            #pragma unroll
            for (int r = 0; r < 4; ++r) x2r[r] += x2part[wv][quad * 4 + r];
            #pragma unroll
            for (int t = 0; t < 4; ++t) p2c[t] += p2part[wv][t * 16 + l15];
        }
        float vc[4];
        #pragma unroll
        for (int t = 0; t < 4; ++t) vc[t] = V[t * 16 + l15];

        float lossAcc = 0.0f;
        #pragma unroll
        for (int r = 0; r < 4; ++r) {
            float lg[4];
            #pragma unroll
            for (int t = 0; t < 4; ++t)
                lg[t] = (2.0f * dsum[t][r] - x2r[r] - p2c[t]) / vc[t];
            float mx = fmaxf(fmaxf(lg[0], lg[1]), fmaxf(lg[2], lg[3]));
            #pragma unroll
            for (int dl = 1; dl <= 8; dl <<= 1) mx = fmaxf(mx, __shfl_xor(mx, dl));
            float s = expf(lg[0] - mx) + expf(lg[1] - mx)
                    + expf(lg[2] - mx) + expf(lg[3] - mx);
            #pragma unroll
            for (int dl = 1; dl <= 8; dl <<= 1) s += __shfl_xor(s, dl);
            const float lse = mx + logf(s);
            const int row = quad * 4 + r;
            #pragma unroll
            for (int t = 0; t < 4; ++t) {
                const int col = t * 16 + l15;
                if (col == y) lossAcc += w * (lse - lg[t]);
                atomicAdd(&predL[row * PSTRIDE + col], w * expf(lg[t] - lse));
            }
        }
        #pragma unroll
        for (int dl = 1; dl <= 32; dl <<= 1) lossAcc += __shfl_xor(lossAcc, dl);
        if (lane == 0) atomicAdd(&lossL, lossAcc);
    }
    __syncthreads();

    if (wave == 0) {
        float cnt = 0.0f;
        #pragma unroll 1
        for (int r = 0; r < 16; ++r) {
            float bv = predL[r * PSTRIDE + lane];
            int   bc = lane;
            #pragma unroll
            for (int dl = 1; dl <= 32; dl <<= 1) {
                const float ov = __shfl_xor(bv, dl);
                const int   oc = __shfl_xor(bc, dl);
                if (ov > bv || (ov == bv && oc < bc)) { bv = ov; bc = oc; }
            }
            if (lane == 0 && bc == y) cnt += 1.0f;
        }
        if (lane == 0) {
            atomicAdd(&out[0], lossL * (1.0f / NROWS));
            atomicAdd(&out[1], cnt * (1.0f / NROWS));
        }
    }
}

extern "C" void kernel_launch(void* const* d_in, const int* in_sizes, int n_in,
                              void* d_out, int out_size, void* d_ws, size_t ws_size,
                              hipStream_t stream) {
    const float* Xtf = (const float*)d_in[0];
    const float* Ptf = (const float*)d_in[1];
    const float* Vtf = (const float*)d_in[2];
    const float* Xde = (const float*)d_in[3];
    const float* Pde = (const float*)d_in[4];
    const float* Vde = (const float*)d_in[5];
    const float* Xff = (const float*)d_in[6];
    const float* Pff = (const float*)d_in[7];
    const float* Vff = (const float*)d_in[8];
    float* out = (float*)d_out;

    if (ws_size >= (size_t)WS_NEED) {
        char* ws = (char*)d_ws;
        _Float16* W    = (_Float16*)(ws + OFF_W);
        float*    p2   = (float*)(ws + OFF_P2);
        float*    pred = (float*)(ws + OFF_PRED);
        float*    lossP= (float*)(ws + OFF_LOSS);
        float*    cntP = (float*)(ws + OFF_CNT);

        hipMemsetAsync(p2, 0, 3 * NCLS * sizeof(float), stream);
        prep_protos<<<dim3(96), dim3(64), 0, stream>>>(Ptf, Pde, Pff, W, p2);
        fusion_main<<<dim3(3 * NRT), dim3(128), 0, stream>>>(
            Xtf, Vtf, Xde, Vde, Xff, Vff, W, p2, pred, lossP);
        finalize1<<<dim3(NROWS / 128), dim3(256), 0, stream>>>(pred, cntP);
        finalize2<<<dim3(1), dim3(256), 0, stream>>>(lossP, cntP, out);
    } else {
        hipMemsetAsync(out, 0, 2 * sizeof(float), stream);
        fusion_loss_fallback<<<dim3(NROWS / 16), dim3(NWAVES * 64), 0, stream>>>(
            Xtf, Ptf, Vtf, Xde, Pde, Vde, Xff, Pff, Vff, out);
    }
}

// Round 6
// 157.061 us; speedup vs baseline: 1.1171x; 1.1171x over previous
//
#include <hip/hip_runtime.h>

// Fusion_loss: 3 modalities of Mahalanobis-distance softmax fusion.
// K=64 classes, Q=128 queries/class, DIM=1024. Rows M = 8192.
// logits_m[r][c] = -(||x_r||^2 - 2 x_r.p_c + ||p_c||^2) / var_c
// loss = mean_r sum_m w_m * (lse_m(r) - logits_m[r][y_r]),  y_r = r/128
// acc  = mean_r [argmax_c sum_m w_m softmax(logits_m)[r][c] == y_r]
//
// R6: occupancy to the 32-wave/CU cap. R5 was 6 blocks/CU (27% occ) with
// 16-way LDS bank conflicts (UW=264 -> 4 clusters; 786k conflict cycles).
// Now: K split across blocks (ks=0/1), 3072 blocks x 4 waves, each wave
// 16 rows x 16 cols (1 MFMA/kc). Partial d-tiles + x2 -> ws (12.8 MB);
// finalize1 does K-combine + softmax + loss + fused argmax; finalize2
// reduces scalars. UW=260 (=4 mod 32): uniform 8 lanes/bank-cluster,
// same as the conflict-free lane-contiguous b128 reference.

typedef _Float16 half8 __attribute__((ext_vector_type(8)));
typedef float    floatx4 __attribute__((ext_vector_type(4)));

#define NCLS   64
#define QPC    128
#define DIM    1024
#define NROWS  (NCLS * QPC)      // 8192
#define NRT    (NROWS / 16)      // 512 row tiles
#define UW     260               // LDS row stride in words (1040 B)

// ws layout
#define OFF_W     0                           // f16 protos, B-frag units
#define W_BYTES   (3 * NCLS * DIM * 2)        // 393216
#define OFF_P2    W_BYTES                     // 768 B
#define OFF_PD    397312                      // 4K-aligned
#define PD_BYTES  (3 * NRT * 2 * 16 * 64 * 4) // 12582912
#define OFF_PX2   (OFF_PD + PD_BYTES)
#define PX2_BYTES (3 * NRT * 2 * 16 * 4)      // 196608
#define OFF_LP    (OFF_PX2 + PX2_BYTES)       // 512 floats
#define OFF_CP    (OFF_LP + NRT * 4)          // 512 floats
#define WS_NEED   (OFF_CP + NRT * 4)

__device__ __forceinline__ void dma16(const float* g, float* l) {
    __builtin_amdgcn_global_load_lds(
        (const __attribute__((address_space(1))) void*)g,
        (__attribute__((address_space(3))) void*)l,
        16, 0, 0);
}

// ---------------- prep: protos -> f16 B-frag layout + p2 ----------------
// Unit (m,kcg,t) = 1KB: lane (l15,quad) holds 8 halves = col t*16+l15,
// k = kcg*32 + quad*8 .. +8.  p2[m*64+c] via atomics.
__global__ __launch_bounds__(64) void prep_protos(
    const float* __restrict__ Ptf, const float* __restrict__ Pde,
    const float* __restrict__ Pff, _Float16* __restrict__ W,
    float* __restrict__ p2)
{
    const int m    = blockIdx.x >> 5;
    const int kcg  = blockIdx.x & 31;
    const int lane = threadIdx.x;
    const int l15  = lane & 15;
    const int quad = lane >> 4;
    const float* __restrict__ P = (m == 0) ? Ptf : (m == 1) ? Pde : Pff;

    #pragma unroll
    for (int t = 0; t < 4; ++t) {
        const float* src = P + (size_t)(t * 16 + l15) * DIM + kcg * 32 + quad * 8;
        const float4 b0 = *reinterpret_cast<const float4*>(src);
        const float4 b1 = *reinterpret_cast<const float4*>(src + 4);
        half8 h;
        h[0] = (_Float16)b0.x; h[1] = (_Float16)b0.y;
        h[2] = (_Float16)b0.z; h[3] = (_Float16)b0.w;
        h[4] = (_Float16)b1.x; h[5] = (_Float16)b1.y;
        h[6] = (_Float16)b1.z; h[7] = (_Float16)b1.w;
        *reinterpret_cast<half8*>(W + ((size_t)(m * 32 + kcg) * 4 + t) * 512 + lane * 8) = h;

        float s = b0.x*b0.x + b0.y*b0.y + b0.z*b0.z + b0.w*b0.w
                + b1.x*b1.x + b1.y*b1.y + b1.z*b1.z + b1.w*b1.w;
        s += __shfl_xor(s, 16);
        s += __shfl_xor(s, 32);
        if (quad == 0) atomicAdd(&p2[m * 64 + t * 16 + l15], s);
    }
}

// ---------------- main: K-split partial GEMM, DMA-staged A ----------------
// block = (m, row-tile, ks); 4 waves; wave w = 16 rows x cols w*16..+15.
__global__ __launch_bounds__(256) void fusion_main(
    const float* __restrict__ Xtf, const float* __restrict__ Xde,
    const float* __restrict__ Xff, const _Float16* __restrict__ W,
    float* __restrict__ pd, float* __restrict__ px2)
{
    __shared__ float chunkBuf[16 * UW];   // 16640 B

    const int tid  = threadIdx.x;
    const int w    = tid >> 6;
    const int lane = tid & 63;
    const int l15  = lane & 15;
    const int quad = lane >> 4;
    const int b    = blockIdx.x;
    const int m    = b >> 10;         // /(512*2)
    const int rt   = (b & 1023) >> 1;
    const int ks   = b & 1;
    const int rowBase = rt * 16;

    const float* __restrict__ X = (m == 0) ? Xtf : (m == 1) ? Xde : Xff;

    floatx4 d = (floatx4){0.f, 0.f, 0.f, 0.f};
    float x2p = 0.0f;

    #pragma unroll 1
    for (int c = 0; c < 2; ++c) {
        if (c) __syncthreads();   // chunk 0 fully consumed before overwrite
        // DMA 4 rows/wave, 1KB lane-contiguous each
        const float* gb = X + (size_t)(rowBase + w * 4) * DIM + ks * 512 + c * 256 + lane * 4;
        #pragma unroll
        for (int r4 = 0; r4 < 4; ++r4)
            dma16(gb + (size_t)r4 * DIM, &chunkBuf[(w * 4 + r4) * UW]);
        __syncthreads();          // drains vmcnt(0): DMA visible

        const int kbase = m * 32 + ks * 16 + c * 8;
        #pragma unroll
        for (int kc = 0; kc < 8; ++kc) {
            const int off = l15 * UW + kc * 32 + quad * 8;
            const float4 a0 = *reinterpret_cast<const float4*>(&chunkBuf[off]);
            const float4 a1 = *reinterpret_cast<const float4*>(&chunkBuf[off + 4]);
            const half8 bf = *reinterpret_cast<const half8*>(
                W + ((size_t)(kbase + kc) * 4 + w) * 512 + lane * 8);

            x2p += a0.x*a0.x + a0.y*a0.y + a0.z*a0.z + a0.w*a0.w
                 + a1.x*a1.x + a1.y*a1.y + a1.z*a1.z + a1.w*a1.w;

            half8 af;
            af[0] = (_Float16)a0.x; af[1] = (_Float16)a0.y;
            af[2] = (_Float16)a0.z; af[3] = (_Float16)a0.w;
            af[4] = (_Float16)a1.x; af[5] = (_Float16)a1.y;
            af[6] = (_Float16)a1.z; af[7] = (_Float16)a1.w;

            d = __builtin_amdgcn_mfma_f32_16x16x32_f16(af, bf, d, 0, 0, 0);
        }
    }

    // x2 of row l15 over this K-half (sum the 4 quad slices)
    x2p += __shfl_xor(x2p, 16);
    x2p += __shfl_xor(x2p, 32);

    const size_t tb = (size_t)((m * NRT + rt) * 2 + ks);
    if (w == 0 && quad == 0) px2[tb * 16 + l15] = x2p;

    float* o = pd + tb * 1024;
    #pragma unroll
    for (int r = 0; r < 4; ++r)
        o[(quad * 4 + r) * 64 + w * 16 + l15] = d[r];   // C-layout: row=quad*4+r, col=l15
}

// ---------------- finalize1: K-combine + softmax + loss + argmax ----------
// block per row-tile; wave v = rows v*4..v*4+3; lane = col.
__global__ __launch_bounds__(256) void finalize1(
    const float* __restrict__ pd, const float* __restrict__ px2,
    const float* __restrict__ p2g,
    const float* __restrict__ Vtf, const float* __restrict__ Vde,
    const float* __restrict__ Vff,
    float* __restrict__ lossPart, float* __restrict__ cntPart)
{
    const int rt   = blockIdx.x;
    const int tid  = threadIdx.x;
    const int v    = tid >> 6;
    const int lane = tid & 63;

    float loss = 0.0f, cnt = 0.0f;
    #pragma unroll
    for (int r4 = 0; r4 < 4; ++r4) {
        const int row = v * 4 + r4;
        const int R   = rt * 16 + row;
        const int y   = R >> 7;
        float pf = 0.0f;
        #pragma unroll
        for (int m = 0; m < 3; ++m) {
            const size_t t0 = (size_t)((m * NRT + rt) * 2);
            const float dsum = pd[t0 * 1024 + row * 64 + lane]
                             + pd[(t0 + 1) * 1024 + row * 64 + lane];
            const float x2 = px2[t0 * 16 + row] + px2[(t0 + 1) * 16 + row];
            const float* __restrict__ V = (m == 0) ? Vtf : (m == 1) ? Vde : Vff;
            const float wgt = (m == 0) ? 1.0f : (m == 1) ? 0.8f : 0.6f;

            const float lg = (2.0f * dsum - x2 - p2g[m * 64 + lane]) / V[lane];
            float mx = lg;
            #pragma unroll
            for (int dl = 1; dl <= 32; dl <<= 1) mx = fmaxf(mx, __shfl_xor(mx, dl));
            float s = expf(lg - mx);
            #pragma unroll
            for (int dl = 1; dl <= 32; dl <<= 1) s += __shfl_xor(s, dl);
            const float lse = mx + logf(s);

            if (lane == y) loss += wgt * (lse - lg);
            pf += wgt * expf(lg - lse);
        }
        // fused argmax, first-max tie-break = lowest col
        float bv = pf; int bc = lane;
        #pragma unroll
        for (int dl = 1; dl <= 32; dl <<= 1) {
            const float ov = __shfl_xor(bv, dl);
            const int   oc = __shfl_xor(bc, dl);
            if (ov > bv || (ov == bv && oc < bc)) { bv = ov; bc = oc; }
        }
        if (lane == 0 && bc == y) cnt += 1.0f;
    }

    #pragma unroll
    for (int dl = 1; dl <= 32; dl <<= 1) {
        loss += __shfl_xor(loss, dl);
        cnt  += __shfl_xor(cnt, dl);
    }
    __shared__ float sl[4], sc[4];
    if (lane == 0) { sl[v] = loss; sc[v] = cnt; }
    __syncthreads();
    if (tid == 0) {
        lossPart[rt] = sl[0] + sl[1] + sl[2] + sl[3];
        cntPart[rt]  = sc[0] + sc[1] + sc[2] + sc[3];
    }
}

// ---------------- finalize2: scalar reduce ----------------
__global__ __launch_bounds__(256) void finalize2(
    const float* __restrict__ lossPart, const float* __restrict__ cntPart,
    float* __restrict__ out)
{
    const int tid  = threadIdx.x;
    const int lane = tid & 63;
    const int v    = tid >> 6;
    float l = 0.0f, c = 0.0f;
    for (int i = tid; i < NRT; i += 256) { l += lossPart[i]; c += cntPart[i]; }
    #pragma unroll
    for (int dl = 1; dl <= 32; dl <<= 1) {
        l += __shfl_xor(l, dl);
        c += __shfl_xor(c, dl);
    }
    __shared__ float sl[4], sc[4];
    if (lane == 0) { sl[v] = l; sc[v] = c; }
    __syncthreads();
    if (tid == 0) {
        out[0] = (sl[0] + sl[1] + sl[2] + sl[3]) * (1.0f / NROWS);
        out[1] = (sc[0] + sc[1] + sc[2] + sc[3]) * (1.0f / NROWS);
    }
}

// ---------------- fallback (R2 kernel, self-contained) ----------------
#define NWAVES 12
#define KSPLIT 4
#define KSLICE (DIM / KSPLIT)
#define NITER  (KSLICE / 32)
#define DSTRIDE 17
#define PSTRIDE 65

__global__ __launch_bounds__(NWAVES * 64) void fusion_loss_fallback(
    const float* __restrict__ Xtf, const float* __restrict__ Ptf, const float* __restrict__ Vtf,
    const float* __restrict__ Xde, const float* __restrict__ Pde, const float* __restrict__ Vde,
    const float* __restrict__ Xff, const float* __restrict__ Pff, const float* __restrict__ Vff,
    float* __restrict__ out)
{
    __shared__ float dpart[NWAVES][64 * DSTRIDE];
    __shared__ float x2part[NWAVES][16];
    __shared__ float p2part[NWAVES][64];
    __shared__ float predL[16 * PSTRIDE];
    __shared__ float lossL;

    const int tid  = threadIdx.x;
    const int wave = tid >> 6;
    const int lane = tid & 63;
    const int l15  = lane & 15;
    const int quad = lane >> 4;
    const int m    = wave >> 2;
    const int kq   = wave & 3;
    const int rowBase = blockIdx.x * 16;

    for (int i = tid; i < 16 * PSTRIDE; i += NWAVES * 64) predL[i] = 0.0f;
    if (tid == 0) lossL = 0.0f;

    const float* __restrict__ X = (m == 0) ? Xtf : (m == 1) ? Xde : Xff;
    const float* __restrict__ P = (m == 0) ? Ptf : (m == 1) ? Pde : Pff;
    const float* __restrict__ V = (m == 0) ? Vtf : (m == 1) ? Vde : Vff;
    const float  w = (m == 0) ? 1.0f : (m == 1) ? 0.8f : 0.6f;

    floatx4 d[4];
    #pragma unroll
    for (int t = 0; t < 4; ++t) d[t] = (floatx4){0.f, 0.f, 0.f, 0.f};
    float x2p    = 0.0f;
    float p2p[4] = {0.f, 0.f, 0.f, 0.f};

    const float* xrow = X + (size_t)(rowBase + l15) * DIM + kq * KSLICE + quad * 8;
    const float* prow[4];
    #pragma unroll
    for (int t = 0; t < 4; ++t)
        prow[t] = P + (size_t)(t * 16 + l15) * DIM + kq * KSLICE + quad * 8;

    #pragma unroll 2
    for (int kc = 0; kc < NITER; ++kc) {
        const int ko = kc * 32;
        const float4 a0 = *reinterpret_cast<const float4*>(xrow + ko);
        const float4 a1 = *reinterpret_cast<const float4*>(xrow + ko + 4);
        float4 b0[4], b1[4];
        #pragma unroll
        for (int t = 0; t < 4; ++t) {
            b0[t] = *reinterpret_cast<const float4*>(prow[t] + ko);
            b1[t] = *reinterpret_cast<const float4*>(prow[t] + ko + 4);
        }
        x2p += a0.x*a0.x + a0.y*a0.y + a0.z*a0.z + a0.w*a0.w
             + a1.x*a1.x + a1.y*a1.y + a1.z*a1.z + a1.w*a1.w;
        half8 af;
        af[0] = (_Float16)a0.x; af[1] = (_Float16)a0.y;
        af[2] = (_Float16)a0.z; af[3] = (_Float16)a0.w;
        af[4] = (_Float16)a1.x; af[5] = (_Float16)a1.y;
        af[6] = (_Float16)a1.z; af[7] = (_Float16)a1.w;
        #pragma unroll
        for (int t = 0; t < 4; ++t) {
            p2p[t] += b0[t].x*b0[t].x + b0[t].y*b0[t].y + b0[t].z*b0[t].z + b0[t].w*b0[t].w
                    + b1[t].x*b1[t].x + b1[t].y*b1[t].y + b1[t].z*b1[t].z + b1[t].w*b1[t].w;
            half8 bf;
            bf[0] = (_Float16)b0[t].x; bf[1] = (_Float16)b0[t].y;
            bf[2] = (_Float16)b0[t].z; bf[3] = (_Float16)b0[t].w;
            bf[4] = (_Float16)b1[t].x; bf[5] = (_Float16)b1[t].y;
            bf[6] = (_Float16)b1[t].z; bf[7] = (_Float16)b1[t].w;
            d[t] = __builtin_amdgcn_mfma_f32_16x16x32_f16(af, bf, d[t], 0, 0, 0);
        }
    }

    x2p += __shfl_xor(x2p, 16);
    x2p += __shfl_xor(x2p, 32);
    #pragma unroll
    for (int t = 0; t < 4; ++t) {
        p2p[t] += __shfl_xor(p2p[t], 16);
        p2p[t] += __shfl_xor(p2p[t], 32);
    }
    {
        float* dp = &dpart[wave][lane * DSTRIDE];
        #pragma unroll
        for (int t = 0; t < 4; ++t)
            *reinterpret_cast<float4*>(dp + t * 4) =
                make_float4(d[t][0], d[t][1], d[t][2], d[t][3]);
        if (quad == 0) {
            x2part[wave][l15] = x2p;
            #pragma unroll
            for (int t = 0; t < 4; ++t) p2part[wave][t * 16 + l15] = p2p[t];
        }
    }
    __syncthreads();

    const int y = rowBase >> 7;

    if (kq == 0) {
        floatx4 dsum[4];
        #pragma unroll
        for (int t = 0; t < 4; ++t) dsum[t] = (floatx4){0.f, 0.f, 0.f, 0.f};
        float x2r[4] = {0.f, 0.f, 0.f, 0.f};
        float p2c[4] = {0.f, 0.f, 0.f, 0.f};
        #pragma unroll
        for (int k2 = 0; k2 < KSPLIT; ++k2) {
            const int wv = m * 4 + k2;
            const float* src = &dpart[wv][lane * DSTRIDE];
            #pragma unroll
            for (int t = 0; t < 4; ++t) {
                const float4 vv = *reinterpret_cast<const float4*>(src + t * 4);
                dsum[t][0] += vv.x; dsum[t][1] += vv.y; dsum[t][2] += vv.z; dsum[t][3] += vv.w;
            }
            #pragma unroll
            for (int r = 0; r < 4; ++r) x2r[r] += x2part[wv][quad * 4 + r];
            #pragma unroll
            for (int t = 0; t < 4; ++t) p2c[t] += p2part[wv][t * 16 + l15];
        }
        float vc[4];
        #pragma unroll
        for (int t = 0; t < 4; ++t) vc[t] = V[t * 16 + l15];

        float lossAcc = 0.0f;
        #pragma unroll
        for (int r = 0; r < 4; ++r) {
            float lg[4];
            #pragma unroll
            for (int t = 0; t < 4; ++t)
                lg[t] = (2.0f * dsum[t][r] - x2r[r] - p2c[t]) / vc[t];
            float mx = fmaxf(fmaxf(lg[0], lg[1]), fmaxf(lg[2], lg[3]));
            #pragma unroll
            for (int dl = 1; dl <= 8; dl <<= 1) mx = fmaxf(mx, __shfl_xor(mx, dl));
            float s = expf(lg[0] - mx) + expf(lg[1] - mx)
                    + expf(lg[2] - mx) + expf(lg[3] - mx);
            #pragma unroll
            for (int dl = 1; dl <= 8; dl <<= 1) s += __shfl_xor(s, dl);
            const float lse = mx + logf(s);
            const int row = quad * 4 + r;
            #pragma unroll
            for (int t = 0; t < 4; ++t) {
                const int col = t * 16 + l15;
                if (col == y) lossAcc += w * (lse - lg[t]);
                atomicAdd(&predL[row * PSTRIDE + col], w * expf(lg[t] - lse));
            }
        }
        #pragma unroll
        for (int dl = 1; dl <= 32; dl <<= 1) lossAcc += __shfl_xor(lossAcc, dl);
        if (lane == 0) atomicAdd(&lossL, lossAcc);
    }
    __syncthreads();

    if (wave == 0) {
        float cnt = 0.0f;
        #pragma unroll 1
        for (int r = 0; r < 16; ++r) {
            float bv = predL[r * PSTRIDE + lane];
            int   bc = lane;
            #pragma unroll
            for (int dl = 1; dl <= 32; dl <<= 1) {
                const float ov = __shfl_xor(bv, dl);
                const int   oc = __shfl_xor(bc, dl);
                if (ov > bv || (ov == bv && oc < bc)) { bv = ov; bc = oc; }
            }
            if (lane == 0 && bc == y) cnt += 1.0f;
        }
        if (lane == 0) {
            atomicAdd(&out[0], lossL * (1.0f / NROWS));
            atomicAdd(&out[1], cnt * (1.0f / NROWS));
        }
    }
}

extern "C" void kernel_launch(void* const* d_in, const int* in_sizes, int n_in,
                              void* d_out, int out_size, void* d_ws, size_t ws_size,
                              hipStream_t stream) {
    const float* Xtf = (const float*)d_in[0];
    const float* Ptf = (const float*)d_in[1];
    const float* Vtf = (const float*)d_in[2];
    const float* Xde = (const float*)d_in[3];
    const float* Pde = (const float*)d_in[4];
    const float* Vde = (const float*)d_in[5];
    const float* Xff = (const float*)d_in[6];
    const float* Pff = (const float*)d_in[7];
    const float* Vff = (const float*)d_in[8];
    float* out = (float*)d_out;

    if (ws_size >= (size_t)WS_NEED) {
        char* ws = (char*)d_ws;
        _Float16* W     = (_Float16*)(ws + OFF_W);
        float*    p2    = (float*)(ws + OFF_P2);
        float*    pd    = (float*)(ws + OFF_PD);
        float*    px2   = (float*)(ws + OFF_PX2);
        float*    lossP = (float*)(ws + OFF_LP);
        float*    cntP  = (float*)(ws + OFF_CP);

        hipMemsetAsync(p2, 0, 3 * NCLS * sizeof(float), stream);
        prep_protos<<<dim3(96), dim3(64), 0, stream>>>(Ptf, Pde, Pff, W, p2);
        fusion_main<<<dim3(3 * NRT * 2), dim3(256), 0, stream>>>(
            Xtf, Xde, Xff, W, pd, px2);
        finalize1<<<dim3(NRT), dim3(256), 0, stream>>>(
            pd, px2, p2, Vtf, Vde, Vff, lossP, cntP);
        finalize2<<<dim3(1), dim3(256), 0, stream>>>(lossP, cntP, out);
    } else {
        hipMemsetAsync(out, 0, 2 * sizeof(float), stream);
        fusion_loss_fallback<<<dim3(NROWS / 16), dim3(NWAVES * 64), 0, stream>>>(
            Xtf, Ptf, Vtf, Xde, Pde, Vde, Xff, Pff, Vff, out);
    }
}